// Round 1
// baseline (75.269 us; speedup 1.0000x reference)
//
#include <hip/hip_runtime.h>

// MOLGCirculantLinear: fused circular-conv (k=8) + poly + clamp + scale + photodetect.
// Shapes: x[512][1024] f32, weight[128][128][8] f32, scale[64][8] f32.
// Outputs concatenated in d_out: out[512][1024] (524288 f32) then phase[512][128][128][8].

#define NB    512
#define NGY   128
#define NGX   128
#define NK    8

__global__ __launch_bounds__(256, 4) void molg_fused(
    const float* __restrict__ x,
    const float* __restrict__ w,
    const float* __restrict__ scale,
    float* __restrict__ d_out)
{
    const int lane = threadIdx.x & 63;
    const int wave = threadIdx.x >> 6;
    const int pair = blockIdx.x;            // 0 .. 512*32-1
    const int b    = pair >> 5;             // 32 gy-groups per batch row
    const int gy   = ((pair & 31) << 2) + wave;

    float* out   = d_out;
    float* phase = d_out + (size_t)NB * NGY * NK;   // 524288

    const float c0 = 0.02403f, c1 = -0.2699f, c2 = 1.17f,
                c3 = -2.454f,  c4 = 2.523f,  c5 = -0.08003f;

    float acc[NK];
#pragma unroll
    for (int i = 0; i < NK; ++i) acc[i] = 0.f;

#pragma unroll
    for (int it = 0; it < 2; ++it) {
        const int gx = lane + 64 * it;

        // load x chunk (8 f32) and square it
        const float4* x4 = reinterpret_cast<const float4*>(x + (size_t)b * 1024 + gx * NK);
        float4 xa = x4[0], xb = x4[1];
        float x2[NK] = {xa.x * xa.x, xa.y * xa.y, xa.z * xa.z, xa.w * xa.w,
                        xb.x * xb.x, xb.y * xb.y, xb.z * xb.z, xb.w * xb.w};

        // load weight chunk (8 f32)
        const float4* w4 = reinterpret_cast<const float4*>(w + ((size_t)gy * NGX + gx) * NK);
        float4 wa = w4[0], wb = w4[1];
        float wv[NK] = {wa.x, wa.y, wa.z, wa.w, wb.x, wb.y, wb.z, wb.w};

        // circular convolution: xr[n] = sum_m wv[m] * x2[(n-m) mod 8]
        float xr[NK];
#pragma unroll
        for (int n = 0; n < NK; ++n) {
            float s = 0.f;
#pragma unroll
            for (int m = 0; m < NK; ++m)
                s = fmaf(wv[m], x2[(n - m) & 7], s);
            xr[n] = s;
        }

        // phase output: coalesced 2KB per wave per iteration
        float4* p4 = reinterpret_cast<float4*>(
            phase + (((size_t)b * NGY + gy) * NGX + gx) * NK);
        p4[0] = make_float4(xr[0], xr[1], xr[2], xr[3]);
        p4[1] = make_float4(xr[4], xr[5], xr[6], xr[7]);

        // scale (tiled: s[gx] = scale[gx & 63])
        const float4* s4 = reinterpret_cast<const float4*>(scale + (size_t)(gx & 63) * NK);
        float4 sa = s4[0], sb = s4[1];
        float sv[NK] = {sa.x, sa.y, sa.z, sa.w, sb.x, sb.y, sb.z, sb.w};

        // poly (Horner, degree 5) -> clamp [0,1] -> * scale -> accumulate
#pragma unroll
        for (int n = 0; n < NK; ++n) {
            float p = fmaf(c0, xr[n], c1);
            p = fmaf(p, xr[n], c2);
            p = fmaf(p, xr[n], c3);
            p = fmaf(p, xr[n], c4);
            p = fmaf(p, xr[n], c5);
            p = fminf(fmaxf(p, 0.f), 1.f);
            acc[n] = fmaf(p, sv[n], acc[n]);
        }
    }

    // butterfly reduce across the wave's 64 lanes (sums over all 128 gx)
#pragma unroll
    for (int off = 1; off < 64; off <<= 1) {
#pragma unroll
        for (int n = 0; n < NK; ++n)
            acc[n] += __shfl_xor(acc[n], off, 64);
    }

    // out[b, gy*8 + k] = 2 * sum_gx(xm) - 128
    if (lane == 0) {
        float4* o4 = reinterpret_cast<float4*>(out + (size_t)b * 1024 + gy * NK);
        o4[0] = make_float4(2.f * acc[0] - 128.f, 2.f * acc[1] - 128.f,
                            2.f * acc[2] - 128.f, 2.f * acc[3] - 128.f);
        o4[1] = make_float4(2.f * acc[4] - 128.f, 2.f * acc[5] - 128.f,
                            2.f * acc[6] - 128.f, 2.f * acc[7] - 128.f);
    }
}

extern "C" void kernel_launch(void* const* d_in, const int* in_sizes, int n_in,
                              void* d_out, int out_size, void* d_ws, size_t ws_size,
                              hipStream_t stream) {
    const float* x     = (const float*)d_in[0];   // 512*1024
    const float* w     = (const float*)d_in[1];   // 128*128*8
    const float* scale = (const float*)d_in[2];   // 64*8
    float* out = (float*)d_out;

    dim3 grid(NB * (NGY / 4));   // 16384 blocks, one wave per (b, gy)
    dim3 block(256);
    hipLaunchKernelGGL(molg_fused, grid, block, 0, stream, x, w, scale, out);
}